// Round 1
// baseline (3690.120 us; speedup 1.0000x reference)
//
#include <hip/hip_runtime.h>

#define NT     512          // threads per block (8 waves)
#define PH     128
#define PW     128
#define NPIX   (PH*PW)      // 16384
#define PER_T  (NPIX/NT)    // 32 pixels per thread
#define NBF    (NPIX/2)     // 8192 butterflies per stage
#define BF_T   (NBF/NT)     // 16 butterflies per thread per stage
#define NSLICES 8
#define NMODES  4
#define OBJH   512
#define OBJW   512

__device__ __forceinline__ float2 cmul(float2 a, float2 b) {
    return make_float2(a.x*b.x - a.y*b.y, a.x*b.y + a.y*b.x);
}

// ---- radix-2 FFT stages over LDS image -------------------------------------
// Forward: DIF (Gentleman-Sande), spans 64..1, natural in -> bit-reversed out.
// Inverse: DIT (Cooley-Tukey), spans 1..64, bit-reversed in -> natural out
//          (1/N scaling folded into the propagator).
// twid[j] = exp(-2*pi*i*j/128), j in [0,64). Stage span S uses twid[j<<(6-ls)].

__device__ __forceinline__ void fft2_fwd(float2* img, const float2* twid, int t) {
    // row pass (along w)
    for (int ls = 6; ls >= 0; --ls) {
        const int S = 1 << ls;
        #pragma unroll
        for (int i = 0; i < BF_T; i++) {
            int b   = t + i*NT;
            int row = b >> 6;            // 64 butterflies per row
            int p   = b & 63;
            int j   = p & (S-1);
            int g   = p >> ls;
            int i0  = (row << 7) + g*(S<<1) + j;
            int i1  = i0 + S;
            float2 u = img[i0], v = img[i1];
            img[i0] = make_float2(u.x+v.x, u.y+v.y);
            float2 d = make_float2(u.x-v.x, u.y-v.y);
            img[i1] = cmul(d, twid[j << (6-ls)]);
        }
        __syncthreads();
    }
    // column pass (along h)
    for (int ls = 6; ls >= 0; --ls) {
        const int S = 1 << ls;
        #pragma unroll
        for (int i = 0; i < BF_T; i++) {
            int b   = t + i*NT;
            int col = b & 127;           // consecutive lanes -> consecutive cols
            int p   = b >> 7;
            int j   = p & (S-1);
            int g   = p >> ls;
            int i0  = ((g*(S<<1) + j) << 7) + col;
            int i1  = i0 + (S << 7);
            float2 u = img[i0], v = img[i1];
            img[i0] = make_float2(u.x+v.x, u.y+v.y);
            float2 d = make_float2(u.x-v.x, u.y-v.y);
            img[i1] = cmul(d, twid[j << (6-ls)]);
        }
        __syncthreads();
    }
}

__device__ __forceinline__ void fft2_inv(float2* img, const float2* twid, int t) {
    // row pass
    for (int ls = 0; ls <= 6; ++ls) {
        const int S = 1 << ls;
        #pragma unroll
        for (int i = 0; i < BF_T; i++) {
            int b   = t + i*NT;
            int row = b >> 6;
            int p   = b & 63;
            int j   = p & (S-1);
            int g   = p >> ls;
            int i0  = (row << 7) + g*(S<<1) + j;
            int i1  = i0 + S;
            float2 w = twid[j << (6-ls)];
            w.y = -w.y;                          // conj -> inverse
            float2 u = img[i0];
            float2 v = cmul(img[i1], w);
            img[i0] = make_float2(u.x+v.x, u.y+v.y);
            img[i1] = make_float2(u.x-v.x, u.y-v.y);
        }
        __syncthreads();
    }
    // column pass
    for (int ls = 0; ls <= 6; ++ls) {
        const int S = 1 << ls;
        #pragma unroll
        for (int i = 0; i < BF_T; i++) {
            int b   = t + i*NT;
            int col = b & 127;
            int p   = b >> 7;
            int j   = p & (S-1);
            int g   = p >> ls;
            int i0  = ((g*(S<<1) + j) << 7) + col;
            int i1  = i0 + (S << 7);
            float2 w = twid[j << (6-ls)];
            w.y = -w.y;
            float2 u = img[i0];
            float2 v = cmul(img[i1], w);
            img[i0] = make_float2(u.x+v.x, u.y+v.y);
            img[i1] = make_float2(u.x-v.x, u.y-v.y);
        }
        __syncthreads();
    }
}

// ---- main kernel: one block per scan position ------------------------------
__global__ void __launch_bounds__(NT, 2)
multislice_kernel(const float* __restrict__ probe_re,
                  const float* __restrict__ probe_im,
                  const float* __restrict__ obj_re,
                  const float* __restrict__ obj_im,
                  const int*   __restrict__ positions,
                  float*       __restrict__ out)
{
    __shared__ float2 s_img[NPIX];   // 128 KB: whole complex image
    __shared__ float2 s_twid[64];    // W_128^j table

    const int n = blockIdx.x;
    const int t = threadIdx.x;
    const int py = positions[2*n];
    const int px = positions[2*n + 1];

    if (t < 64) {
        float ang = -2.0f * 3.14159265358979323846f * (float)t / 128.0f;
        float s, c;
        sincosf(ang, &s, &c);
        s_twid[t] = make_float2(c, s);
    }

    // Per-thread propagator values in BIT-REVERSED layout (matches the data
    // between fwd-DIF and inv-DIT), with ifft2's 1/16384 folded in.
    float2 propv[PER_T];
    #pragma unroll
    for (int k = 0; k < PER_T; k++) {
        int q  = t + k*NT;
        int rh = q >> 7, rw = q & 127;
        int h  = __brev((unsigned)rh) >> 25;   // 7-bit reverse
        int w  = __brev((unsigned)rw) >> 25;
        float fy = (float)(h < 64 ? h : h - 128) * (1.0f / 25.6f);  // fftfreq/d, d=0.2
        float fx = (float)(w < 64 ? w : w - 128) * (1.0f / 25.6f);
        float phase = -0.15707963267948966f * (fy*fy + fx*fx);      // -pi*wl*dz*k2
        float s, c;
        sincosf(phase, &s, &c);
        propv[k] = make_float2(c * (1.0f/16384.0f), s * (1.0f/16384.0f));
    }

    float acc[PER_T];
    #pragma unroll
    for (int k = 0; k < PER_T; k++) acc[k] = 0.0f;

    for (int m = 0; m < NMODES; m++) {
        __syncthreads();   // twid visible / previous-m reads done
        // ex = probe[m] * patch(slice 0)
        #pragma unroll
        for (int k = 0; k < PER_T; k++) {
            int q  = t + k*NT;
            int oh = q >> 7, ow = q & 127;
            float2 p = make_float2(probe_re[m*NPIX + q], probe_im[m*NPIX + q]);
            int oidx = (py + oh)*OBJW + (px + ow);           // slice 0
            float2 o = make_float2(obj_re[oidx], obj_im[oidx]);
            s_img[q] = cmul(p, o);
        }
        __syncthreads();

        for (int s = 1; s < NSLICES; s++) {
            fft2_fwd(s_img, s_twid, t);          // ends with syncthreads
            #pragma unroll
            for (int k = 0; k < PER_T; k++) {    // * prop (bit-reversed layout)
                int q = t + k*NT;
                s_img[q] = cmul(s_img[q], propv[k]);
            }
            __syncthreads();
            fft2_inv(s_img, s_twid, t);          // ends with syncthreads
            #pragma unroll
            for (int k = 0; k < PER_T; k++) {    // * patch(slice s), natural order
                int q  = t + k*NT;
                int oh = q >> 7, ow = q & 127;
                int oidx = (s*OBJH + py + oh)*OBJW + (px + ow);
                float2 o = make_float2(obj_re[oidx], obj_im[oidx]);
                s_img[q] = cmul(s_img[q], o);
            }
            __syncthreads();
        }

        fft2_fwd(s_img, s_twid, t);              // final FFT, bit-reversed out
        // accumulate |.|^2 with fused bitrev + fftshift:
        // out(oh,ow) <- storage(bitrev7(oh)^1, bitrev7(ow)^1)
        #pragma unroll
        for (int k = 0; k < PER_T; k++) {
            int q  = t + k*NT;
            int oh = q >> 7, ow = q & 127;
            int rh = (__brev((unsigned)oh) >> 25) ^ 1;
            int rw = (__brev((unsigned)ow) >> 25) ^ 1;
            float2 v = s_img[(rh << 7) + rw];
            acc[k] += v.x*v.x + v.y*v.y;
        }
    }

    const long long base = (long long)n * NPIX;
    #pragma unroll
    for (int k = 0; k < PER_T; k++) {
        out[base + t + k*NT] = acc[k];
    }
}

extern "C" void kernel_launch(void* const* d_in, const int* in_sizes, int n_in,
                              void* d_out, int out_size, void* d_ws, size_t ws_size,
                              hipStream_t stream) {
    const float* probe_re = (const float*)d_in[0];
    const float* probe_im = (const float*)d_in[1];
    const float* obj_re   = (const float*)d_in[2];
    const float* obj_im   = (const float*)d_in[3];
    const int*   pos      = (const int*)d_in[4];
    float* out = (float*)d_out;

    const int N = out_size / NPIX;   // 512 positions
    multislice_kernel<<<dim3(N), dim3(NT), 0, stream>>>(
        probe_re, probe_im, obj_re, obj_im, pos, out);
}

// Round 2
// 1684.211 us; speedup vs baseline: 2.1910x; 2.1910x over previous
//
#include <hip/hip_runtime.h>
#include <math.h>

#define NT      512
#define NPIX    16384
#define LDP     129          // padded leading dim (float2 units)
#define NSLICES 8
#define NMODES  4
#define OBJW    512

// ---- complex helpers -------------------------------------------------------
__device__ __forceinline__ float2 cmul(float2 a, float2 b) {
    return make_float2(fmaf(a.x, b.x, -a.y * b.y), fmaf(a.x, b.y, a.y * b.x));
}

// 5-bit reversal, constexpr so unrolled uses fold to literals
__host__ __device__ constexpr int BR5(int p) {
    return ((p & 1) << 4) | ((p & 2) << 2) | (p & 4) | ((p & 8) >> 2) | ((p & 16) >> 4);
}

// W32^k = exp(-2*pi*i*k/32) tables (cos, sin) — folded as literals when unrolled
__device__ __constant__ float TWC[16] = {
    1.0f, 0.980785280f, 0.923879533f, 0.831469612f, 0.707106781f, 0.555570233f,
    0.382683432f, 0.195090322f, 0.0f, -0.195090322f, -0.382683432f,
    -0.555570233f, -0.707106781f, -0.831469612f, -0.923879533f, -0.980785280f };
__device__ __constant__ float TWS[16] = {
    0.0f, 0.195090322f, 0.382683432f, 0.555570233f, 0.707106781f, 0.831469612f,
    0.923879533f, 0.980785280f, 1.0f, 0.980785280f, 0.923879533f, 0.831469612f,
    0.707106781f, 0.555570233f, 0.382683432f, 0.195090322f };

// ---- local 32-point FFT in registers ---------------------------------------
// Forward DIF: natural input in v[i]; output v[p] = X[BR5(p)].
__device__ __forceinline__ void fft32_fwd(float2 v[32]) {
    #pragma unroll
    for (int s = 16; s >= 1; s >>= 1) {
        #pragma unroll
        for (int q = 0; q < 32; q += 2 * s) {
            #pragma unroll
            for (int j = 0; j < s; j++) {
                const int tw = j * (16 / s);
                float2 u = v[q + j], w = v[q + j + s];
                v[q + j] = make_float2(u.x + w.x, u.y + w.y);
                float dx = u.x - w.x, dy = u.y - w.y;
                // d * exp(-i theta) = (dx*c + dy*s, dy*c - dx*s)
                v[q + j + s] = make_float2(fmaf(dx, TWC[tw],  dy * TWS[tw]),
                                           fmaf(dy, TWC[tw], -dx * TWS[tw]));
            }
        }
    }
}

// Inverse DIT (unnormalized): input v[p] = Y[BR5(p)]; output natural y[i].
__device__ __forceinline__ void fft32_inv(float2 v[32]) {
    #pragma unroll
    for (int s = 1; s <= 16; s <<= 1) {
        #pragma unroll
        for (int q = 0; q < 32; q += 2 * s) {
            #pragma unroll
            for (int j = 0; j < s; j++) {
                const int tw = j * (16 / s);
                float2 u = v[q + j], w = v[q + j + s];
                // t = w * exp(+i theta) = (w.x*c - w.y*s, w.y*c + w.x*s)
                float2 tv = make_float2(fmaf(w.x, TWC[tw], -w.y * TWS[tw]),
                                        fmaf(w.y, TWC[tw],  w.x * TWS[tw]));
                v[q + j]     = make_float2(u.x + tv.x, u.y + tv.y);
                v[q + j + s] = make_float2(u.x - tv.x, u.y - tv.y);
            }
        }
    }
}

// ---- cross-thread 4-point FFT over sub-index b (shfl_xor masks 2,1) --------
// Forward DIF-4: input thread b holds n1=b; output thread b holds k1=br2(b).
__device__ __forceinline__ void cross4_fwd(float2 v[32], int b) {
    const float sA = (b < 2) ? 1.0f : -1.0f;
    const bool rot3 = (b == 3);
    const float sB = ((b & 1) == 0) ? 1.0f : -1.0f;
    #pragma unroll
    for (int p = 0; p < 32; p++) {
        float ox = __shfl_xor(v[p].x, 2), oy = __shfl_xor(v[p].y, 2);
        float nx = fmaf(sA, v[p].x, ox), ny = fmaf(sA, v[p].y, oy);
        float rx = rot3 ?  ny : nx;            // b==3: *(-i): (x,y)->(y,-x)
        float ry = rot3 ? -nx : ny;
        ox = __shfl_xor(rx, 1); oy = __shfl_xor(ry, 1);
        v[p].x = fmaf(sB, rx, ox); v[p].y = fmaf(sB, ry, oy);
    }
}

// Inverse DIT-4 (unnormalized): input thread b holds k1=br2(b); output n1=b.
__device__ __forceinline__ void cross4_inv(float2 v[32], int b) {
    const float sA = ((b & 1) == 0) ? 1.0f : -1.0f;
    const bool rot3 = (b == 3);
    const float sB = (b < 2) ? 1.0f : -1.0f;
    #pragma unroll
    for (int p = 0; p < 32; p++) {
        float ox = __shfl_xor(v[p].x, 1), oy = __shfl_xor(v[p].y, 1);
        float nx = fmaf(sA, v[p].x, ox), ny = fmaf(sA, v[p].y, oy);
        float rx = rot3 ? -ny : nx;            // b==3: *(+i): (x,y)->(-y,x)
        float ry = rot3 ?  nx : ny;
        ox = __shfl_xor(rx, 2); oy = __shfl_xor(ry, 2);
        v[p].x = fmaf(sB, rx, ox); v[p].y = fmaf(sB, ry, oy);
    }
}

// ---- full 128-point pass: local FFT32 + W128 twiddle + cross FFT4 ----------
// State convention: reg j holds element (b + 4j); after fwd, reg p holds
// k = BR5(p) + 32*br2(b).
__device__ __forceinline__ void pass_fwd(float2 v[32], int b, const float2* t128) {
    fft32_fwd(v);
    #pragma unroll
    for (int p = 0; p < 32; p++) {
        float2 w = t128[b * BR5(p)];
        v[p] = cmul(v[p], w);
    }
    cross4_fwd(v, b);
}
__device__ __forceinline__ void pass_inv(float2 v[32], int b, const float2* t128) {
    cross4_inv(v, b);
    #pragma unroll
    for (int p = 0; p < 32; p++) {
        float2 w = t128[b * BR5(p)];
        v[p] = cmul(v[p], make_float2(w.x, -w.y));   // conj
    }
    fft32_inv(v);
}

// ---- main kernel: one block per scan position ------------------------------
__global__ void __launch_bounds__(NT, 2)
multislice_kernel(const float* __restrict__ probe_re,
                  const float* __restrict__ probe_im,
                  const float* __restrict__ obj_re,
                  const float* __restrict__ obj_im,
                  const int*   __restrict__ positions,
                  float*       __restrict__ out)
{
    __shared__ float2 LT[128 * LDP];   // 132096 B transpose buffer
    __shared__ float2 t128[128];       // W128^i
    __shared__ float2 pyt[128];        // prop y-factor * (1/16384)

    const int t  = threadIdx.x;
    const int g  = t >> 2;             // group: row (R-state) / column (C-state)
    const int b  = t & 3;              // sub-index within 128-FFT
    const int rb = ((b & 1) << 1) | (b >> 1);   // br2(b)
    const int n  = blockIdx.x;
    const int Y0 = positions[2 * n];
    const int X0 = positions[2 * n + 1];

    if (t < 128) {
        float ang = -2.0f * 3.14159265358979323846f * (float)t / 128.0f;
        float s, c; __sincosf(ang, &s, &c);
        t128[t] = make_float2(c, s);
        float fy = (float)(t < 64 ? t : t - 128) * (1.0f / 25.6f);
        float ph = -0.15707963267948966f * fy * fy;   // -pi*wl*dz * fy^2
        float ps, pc; __sincosf(ph, &ps, &pc);
        pyt[t] = make_float2(pc * (1.0f / 16384.0f), ps * (1.0f / 16384.0f));
    }
    // per-thread x-factor of the propagator (column kw = g is fixed in C-state)
    float fx = (float)(g < 64 ? g : g - 128) * (1.0f / 25.6f);
    float phx = -0.15707963267948966f * fx * fx;
    float pxs, pxc; __sincosf(phx, &pxs, &pxc);
    const float2 px = make_float2(pxc, pxs);
    __syncthreads();

    float acc[32];
    #pragma unroll
    for (int p = 0; p < 32; p++) acc[p] = 0.0f;

    float2 v[32];

    for (int m = 0; m < NMODES; m++) {
        // R-state load: ex = probe[m] * patch(slice0); reg j: (row g, w=b+4j)
        #pragma unroll
        for (int j = 0; j < 32; j++) {
            int w  = b + 4 * j;
            int pi = m * NPIX + g * 128 + w;
            float2 pr = make_float2(probe_re[pi], probe_im[pi]);
            int oi = (Y0 + g) * OBJW + (X0 + w);
            float2 ob = make_float2(obj_re[oi], obj_im[oi]);
            v[j] = cmul(pr, ob);
        }

        for (int s = 1; s < NSLICES; s++) {
            pass_fwd(v, b, t128);                       // Fw: (r=g, kw=perm)
            #pragma unroll                              // T1 write: LT[kw][r]
            for (int p = 0; p < 32; p++)
                LT[(BR5(p) + 32 * rb) * LDP + g] = v[p];
            __syncthreads();
            #pragma unroll                              // T1 read -> C-state
            for (int j = 0; j < 32; j++)
                v[j] = LT[g * LDP + b + 4 * j];
            __syncthreads();
            pass_fwd(v, b, t128);                       // Fh: (kh=perm, kw=g)
            #pragma unroll                              // * prop (py*px)
            for (int p = 0; p < 32; p++) {
                float2 pp = cmul(pyt[BR5(p) + 32 * rb], px);
                v[p] = cmul(v[p], pp);
            }
            pass_inv(v, b, t128);                       // iFh: (r=b+4j, kw=g)
            #pragma unroll                              // T2 write: LT[r][kw]
            for (int j = 0; j < 32; j++)
                LT[(b + 4 * j) * LDP + g] = v[j];
            __syncthreads();
            #pragma unroll                              // T2 read -> R-state(perm)
            for (int p = 0; p < 32; p++)
                v[p] = LT[g * LDP + BR5(p) + 32 * rb];
            __syncthreads();
            pass_inv(v, b, t128);                       // iFw: (r=g, w=b+4j)
            #pragma unroll                              // * patch(slice s)
            for (int j = 0; j < 32; j++) {
                int w  = b + 4 * j;
                int oi = (s * OBJW + Y0 + g) * OBJW + (X0 + w);
                float2 ob = make_float2(obj_re[oi], obj_im[oi]);
                v[j] = cmul(v[j], ob);
            }
        }

        // final FFT2: Fw, transpose, Fh, accumulate |.|^2
        pass_fwd(v, b, t128);
        #pragma unroll
        for (int p = 0; p < 32; p++)
            LT[(BR5(p) + 32 * rb) * LDP + g] = v[p];
        __syncthreads();
        #pragma unroll
        for (int j = 0; j < 32; j++)
            v[j] = LT[g * LDP + b + 4 * j];
        __syncthreads();
        pass_fwd(v, b, t128);
        #pragma unroll
        for (int p = 0; p < 32; p++)
            acc[p] += v[p].x * v[p].x + v[p].y * v[p].y;
    }

    // store with fftshift: (kh,kw) -> (kh^64, kw^64); kh = BR5(p)+32*rb, kw = g
    const long long base = (long long)n * NPIX;
    #pragma unroll
    for (int p = 0; p < 32; p++) {
        int kh = BR5(p) + 32 * rb;
        out[base + (long long)((kh ^ 64) * 128 + (g ^ 64))] = acc[p];
    }
}

extern "C" void kernel_launch(void* const* d_in, const int* in_sizes, int n_in,
                              void* d_out, int out_size, void* d_ws, size_t ws_size,
                              hipStream_t stream) {
    const float* probe_re = (const float*)d_in[0];
    const float* probe_im = (const float*)d_in[1];
    const float* obj_re   = (const float*)d_in[2];
    const float* obj_im   = (const float*)d_in[3];
    const int*   pos      = (const int*)d_in[4];
    float* out = (float*)d_out;

    const int N = out_size / NPIX;   // 512 positions
    multislice_kernel<<<dim3(N), dim3(NT), 0, stream>>>(
        probe_re, probe_im, obj_re, obj_im, pos, out);
}